// Round 6
// baseline (29205.630 us; speedup 1.0000x reference)
//
#include <hip/hip_runtime.h>

#define NB 64
#define NNODE 1085
#define HIST 24
#define PRED 24
#define KHOP 3
#define HDIM 64
#define FXD 1
#define FMD 11
#define FD 12
#define NE 17360
#define NROWS (NB*NNODE)   // 69440
#define WPAR 1024          // waves per t-slice (hist gather)
#define WPAR2 8192         // waves per t-slice (pred gather, fine)

// Layout: node tensors are (t, n, f, b) : addr = ((t*NNODE + n)*FD + f)*64 + b
// row-major rows are row = n*64 + b. h is (k, row, HDIM).

typedef float v4 __attribute__((ext_vector_type(4)));

__device__ __forceinline__ float sigm(float x){ return 1.0f/(1.0f + __expf(-x)); }
__device__ __forceinline__ float tanh_f(float x){ return 1.0f - 2.0f/(__expf(2.0f*x)+1.0f); }

// ---------------- CSR build (once per launch) ----------------
__global__ void csr_count_k(const int* __restrict__ dst, int* __restrict__ deg)
{
    int e = blockIdx.x*256 + threadIdx.x;
    if (e < NE) atomicAdd(&deg[dst[e]], 1);
}

__global__ __launch_bounds__(1024) void csr_scan_k(const int* __restrict__ deg,
                                                   int* __restrict__ offs, int* __restrict__ curs)
{
    __shared__ int s[2][2048];
    int t = threadIdx.x;
    for (int i=t;i<2048;i+=1024) s[0][i] = (i<NNODE) ? deg[i] : 0;
    __syncthreads();
    int cur = 0;
    for (int d=1; d<2048; d<<=1){
        for (int i=t;i<2048;i+=1024){
            int v = s[cur][i];
            if (i>=d) v += s[cur][i-d];
            s[cur^1][i] = v;
        }
        __syncthreads();
        cur ^= 1;
    }
    for (int i=t;i<=NNODE;i+=1024){
        int v = (i==0) ? 0 : s[cur][i-1];
        offs[i] = v;
        if (i<NNODE) curs[i] = v;
    }
}

__global__ void csr_fill_k(const int* __restrict__ dst, const int* __restrict__ src,
                           int* __restrict__ curs, int* __restrict__ esrc)
{
    int e = blockIdx.x*256 + threadIdx.x;
    if (e < NE){
        int d = dst[e];
        int p = atomicAdd(&curs[d], 1);
        esrc[p] = src[e];
    }
}

// degree-balanced wave->node-range partition (generalized)
__global__ void csr_part_k(const int* __restrict__ offs, int* __restrict__ wpart, int npart)
{
    int w = blockIdx.x*256 + threadIdx.x;
    if (w > npart) return;
    if (w == 0)     { wpart[0] = 0;         return; }
    if (w == npart) { wpart[npart] = NNODE; return; }
    int target = (int)(((long)w * NE) / npart);
    int lo = 0, hi = NNODE;
    while (lo < hi){ int mid = (lo+hi)>>1; if (offs[mid] >= target) hi = mid; else lo = mid+1; }
    wpart[w] = lo;
}

// ---------------- hist-phase batched feature build ----------------
__global__ void build_hist_k(const float* __restrict__ x_hist, const float* __restrict__ enc_misc,
                             int t0, int T, float* __restrict__ xn_all)
{
    long idx = (long)blockIdx.x*256 + threadIdx.x;
    if (idx >= (long)T*NROWS) return;
    int b = (int)(idx & 63);
    long nn = idx >> 6;
    int ti = (int)(nn / NNODE);
    int n  = (int)(nn - (long)ti*NNODE);
    int t  = t0 + ti;
    float* xp = xn_all + (long)ti*NROWS*FD + (long)n*FD*64 + b;
    xp[0] = x_hist[((long)b*HIST + t)*NNODE + n];
    const float* fp = enc_misc + (((long)b*HIST + (t+1))*NNODE + n)*FMD;
    #pragma unroll
    for (int i=0;i<FMD;i++) xp[(1+i)*64] = fp[i];
}

// ---------------- single-step feature build (pred phase) ----------------
__global__ void build_xn_k(const float* __restrict__ xsrc, int from_xcur,
                           const float* __restrict__ dec, int p,
                           float* __restrict__ xn)
{
    int idx = blockIdx.x*256 + threadIdx.x;
    if (idx >= NROWS) return;
    int b = idx & 63, n = idx >> 6;
    float v0 = from_xcur ? xsrc[idx]
                         : xsrc[((long)b*HIST + (HIST-1))*NNODE + n];
    float* xp = xn + (long)n*FD*64 + b;
    xp[0] = v0;
    const float* fp = dec + (((long)b*PRED + p)*NNODE + n)*FMD;
    #pragma unroll
    for (int i=0;i<FMD;i++) xp[(1+i)*64] = fp[i];
}

// ---------------- GNN hop: lane=batch, wave=node-range, no atomics ----------------
// HISTMODE=1: XCD-bound slices (slice ti -> XCD ti%8; 256 blocks/slice on one XCD,
//             1024-wave partition). HISTMODE=0: single slice spread over all XCDs
//             with fine 8192-wave partition.
template<int HISTMODE>
__global__ __launch_bounds__(256,4) void gnn_gather_t(const float* __restrict__ xin,
    const float* __restrict__ We, const float* __restrict__ be,
    const int* __restrict__ esrc, const int* __restrict__ offs,
    const int* __restrict__ wpart, int T, float* __restrict__ xout)
{
    __shared__ float w_s[288];
    __shared__ float be_s[12];
    const int tid = threadIdx.x;
    for (int i=tid;i<288;i+=256) w_s[i]=We[i];
    if (tid<12) be_s[tid]=be[tid];
    __syncthreads();

    const int lane = tid & 63;
    int ti, wave;
    if (HISTMODE){
        int bid = blockIdx.x;
        int j = bid & 7, li = bid >> 3;
        int s = li >> 8, chunk = li & 255;
        ti = j + 8*s;
        if (ti >= T) return;
        wave = chunk*4 + (tid>>6);               // 0..WPAR-1
    } else {
        ti = 0;
        wave = (blockIdx.x*256 + tid) >> 6;      // 0..WPAR2-1
    }
    const long sbase = (long)ti * ((long)NROWS*FD);
    const float* x = xin + sbase;
    float* xo = xout + sbase;

    const int n0 = wpart[wave], n1 = wpart[wave+1];
    for (int n=n0; n<n1; ++n){
        float xd[12], part[12], acc[12];
        const float* xb = x + (long)n*768 + lane;
        #pragma unroll
        for (int f=0;f<12;f++) xd[f] = xb[f*64];
        #pragma unroll
        for (int f=0;f<12;f++){ part[f]=be_s[f]; acc[f]=0.f; }
        #pragma unroll
        for (int f=0;f<12;f++){
            float xv = xd[f];
            const float* wrow = &w_s[(12+f)*12];
            #pragma unroll
            for (int j2=0;j2<12;j2++) part[j2] += xv*wrow[j2];
        }
        const int e0 = offs[n], e1 = offs[n+1];
        for (int idx=e0; idx<e1; ++idx){
            int s2 = esrc[idx];                   // wave-uniform -> scalar load
            const float* xsb = x + (long)s2*768 + lane;
            float m[12];
            #pragma unroll
            for (int f=0;f<12;f++) m[f]=part[f];
            #pragma unroll
            for (int f=0;f<12;f++){
                float xv = xsb[f*64];
                const float* wrow = &w_s[f*12];
                #pragma unroll
                for (int j2=0;j2<12;j2++) m[j2] += xv*wrow[j2];
            }
            #pragma unroll
            for (int f=0;f<12;f++) acc[f] += fmaxf(m[f],0.f);
        }
        float* xob = xo + (long)n*768 + lane;
        #pragma unroll
        for (int f=0;f<12;f++) xob[f*64] = xd[f] + acc[f];
    }
}

// ---------------- Fused GRU over 3 hops (blockIdx.y = k), tile = one node ----------------
#define KC 44
__global__ __launch_bounds__(256) void gru3_k(
    const float* __restrict__ xg_base, long k_stride,
    const float* __restrict__ xn,
    float* __restrict__ h_base,
    const float* __restrict__ Wx, const float* __restrict__ Wh,
    const float* __restrict__ bx, const float* __restrict__ bh)
{
    const int k = blockIdx.y;
    const int n = blockIdx.x;
    const float* xgn = xg_base + (long)k*k_stride + (long)n*768;
    const float* xnn = xn + (long)n*768;
    float*       hn  = h_base + ((size_t)k*NROWS + (long)n*64)*HDIM;
    const float* wx  = Wx + (size_t)k*24*192;
    const float* wh  = Wh + (size_t)k*64*192;
    const float* bxk = bx + k*192;
    const float* bhk = bh + k*192;

    __shared__ __align__(16) float A_s[KC][64];
    __shared__ __align__(16) float W_s[KC][192];
    const int tid = threadIdx.x;
    const int tx = tid & 15, ty = tid >> 4;

    const v4* wx4 = (const v4*)wx;
    const v4* wh4 = (const v4*)wh;
    const v4* h4  = (const v4*)hn;

    float acc_r[16], acc_z[16], acc_gn[16], acc_ghn[16];
    #pragma unroll
    for (int i=0;i<16;i++){ acc_r[i]=0.f; acc_z[i]=0.f; acc_gn[i]=0.f; acc_ghn[i]=0.f; }

    // ---- chunk 0: A rows 0..11 = xg, 12..23 = xn, 24..43 = h cols 0..19 ----
    for (int i=tid; i<KC*48; i+=256){
        int kk = i/48, q = i - kk*48;
        v4 w = (kk<24) ? wx4[kk*48+q] : wh4[(kk-24)*48+q];
        *(v4*)&W_s[kk][q*4] = w;
    }
    for (int i=tid; i<192; i+=256) ((v4*)A_s)[i]       = ((const v4*)xgn)[i];
    for (int i=tid; i<192; i+=256) ((v4*)A_s)[192+i]   = ((const v4*)xnn)[i];
    for (int i=tid; i<320; i+=256){
        int r = i/5, q = i - r*5;
        v4 v = h4[r*16+q];
        #pragma unroll
        for (int j=0;j<4;j++) A_s[24+4*q+j][r] = v[j];
    }
    __syncthreads();
    #pragma unroll 4
    for (int kk=0;kk<24;kk++){
        v4 av=*(const v4*)&A_s[kk][ty*4];
        v4 wr=*(const v4*)&W_s[kk][tx*4];
        v4 wz=*(const v4*)&W_s[kk][64+tx*4];
        v4 wn=*(const v4*)&W_s[kk][128+tx*4];
        #pragma unroll
        for (int dr=0;dr<4;dr++)
            #pragma unroll
            for (int dc=0;dc<4;dc++){
                acc_r[dr*4+dc]+=av[dr]*wr[dc];
                acc_z[dr*4+dc]+=av[dr]*wz[dc];
                acc_gn[dr*4+dc]+=av[dr]*wn[dc];
            }
    }
    #pragma unroll 4
    for (int kk=24;kk<44;kk++){
        v4 av=*(const v4*)&A_s[kk][ty*4];
        v4 wr=*(const v4*)&W_s[kk][tx*4];
        v4 wz=*(const v4*)&W_s[kk][64+tx*4];
        v4 wn=*(const v4*)&W_s[kk][128+tx*4];
        #pragma unroll
        for (int dr=0;dr<4;dr++)
            #pragma unroll
            for (int dc=0;dc<4;dc++){
                acc_r[dr*4+dc]+=av[dr]*wr[dc];
                acc_z[dr*4+dc]+=av[dr]*wz[dc];
                acc_ghn[dr*4+dc]+=av[dr]*wn[dc];
            }
    }
    __syncthreads();
    // ---- chunk 1: A rows 0..43 = h cols 20..63 ----
    for (int i=tid; i<KC*48; i+=256){
        int kk = i/48, q = i - kk*48;
        *(v4*)&W_s[kk][q*4] = wh4[(20+kk)*48+q];
    }
    for (int i=tid; i<704; i+=256){
        int r = i/11, q = i - r*11;
        v4 v = h4[r*16+5+q];
        #pragma unroll
        for (int j=0;j<4;j++) A_s[4*q+j][r] = v[j];
    }
    __syncthreads();
    #pragma unroll 4
    for (int kk=0;kk<44;kk++){
        v4 av=*(const v4*)&A_s[kk][ty*4];
        v4 wr=*(const v4*)&W_s[kk][tx*4];
        v4 wz=*(const v4*)&W_s[kk][64+tx*4];
        v4 wn=*(const v4*)&W_s[kk][128+tx*4];
        #pragma unroll
        for (int dr=0;dr<4;dr++)
            #pragma unroll
            for (int dc=0;dc<4;dc++){
                acc_r[dr*4+dc]+=av[dr]*wr[dc];
                acc_z[dr*4+dc]+=av[dr]*wz[dc];
                acc_ghn[dr*4+dc]+=av[dr]*wn[dc];
            }
    }

    // ---- epilogue ----
    v4 bxr=*(const v4*)&bxk[tx*4],     bhr=*(const v4*)&bhk[tx*4];
    v4 bxz=*(const v4*)&bxk[64+tx*4],  bhz=*(const v4*)&bhk[64+tx*4];
    v4 bxn=*(const v4*)&bxk[128+tx*4], bhn=*(const v4*)&bhk[128+tx*4];
    #pragma unroll
    for (int dr=0;dr<4;dr++){
        int lr = ty*4 + dr;
        v4 hold = *(const v4*)&hn[lr*HDIM + tx*4];
        v4 hnew;
        #pragma unroll
        for (int dc=0;dc<4;dc++){
            float rr = sigm(acc_r[dr*4+dc] + bxr[dc] + bhr[dc]);
            float zz = sigm(acc_z[dr*4+dc] + bxz[dc] + bhz[dc]);
            float nn = tanh_f(acc_gn[dr*4+dc] + bxn[dc] + rr*(acc_ghn[dr*4+dc] + bhn[dc]));
            hnew[dc] = (1.0f-zz)*nn + zz*hold[dc];
        }
        *(v4*)&hn[lr*HDIM + tx*4] = hnew;
    }
}

// ---------------- fc ----------------
__global__ void fc_k(const float* __restrict__ h, const float* __restrict__ fc_w,
                     const float* __restrict__ fc_b, float* __restrict__ x_cur,
                     float* __restrict__ out, int p)
{
    int idx = blockIdx.x*256+threadIdx.x;
    if (idx>=NROWS) return;
    float acc = fc_b[0];
    #pragma unroll
    for (int k=0;k<3;k++){
        const float* hb = h + ((size_t)k*NROWS + idx)*HDIM;
        const float* wb = fc_w + k*HDIM;
        #pragma unroll
        for (int q=0;q<16;q++){
            v4 hv=*(const v4*)&hb[q*4];
            v4 wv=*(const v4*)&wb[q*4];
            acc += hv[0]*wv[0]+hv[1]*wv[1]+hv[2]*wv[2]+hv[3]*wv[3];
        }
    }
    x_cur[idx]=acc;
    int b = idx & 63, n = idx >> 6;
    out[((long)b*PRED + p)*NNODE + n] = acc;
}

extern "C" void kernel_launch(void* const* d_in, const int* in_sizes, int n_in,
                              void* d_out, int out_size, void* d_ws, size_t ws_size,
                              hipStream_t stream)
{
    const float* x_hist   = (const float*)d_in[0];
    const float* enc_misc = (const float*)d_in[1];
    const float* dec      = (const float*)d_in[2];
    const float* We       = (const float*)d_in[3];
    const float* be       = (const float*)d_in[4];
    const float* Wx       = (const float*)d_in[5];
    const float* Wh       = (const float*)d_in[6];
    const float* bx       = (const float*)d_in[7];
    const float* bh       = (const float*)d_in[8];
    const float* fc_w     = (const float*)d_in[9];
    const float* fc_b     = (const float*)d_in[10];
    const int*   src      = (const int*)d_in[11];
    const int*   dst      = (const int*)d_in[12];
    float* out = (float*)d_out;

    // ---- workspace layout (dynamic hist-batch chunk) ----
    const size_t SZ_T = (size_t)NROWS*FD;
    size_t fixed_f = (size_t)3*NROWS*HDIM + NROWS + 96*1024;
    size_t avail_f = ws_size/4;
    long tc = 1;
    if (avail_f > fixed_f + 4*SZ_T)
        tc = (long)((avail_f - fixed_f) / (4*SZ_T));
    if (tc > HIST-1) tc = HIST-1;
    if (tc < 1) tc = 1;
    const long T_CHUNK = tc;

    float* h      = (float*)d_ws;                       // 3*NROWS*HDIM
    float* x_cur  = h + (size_t)3*NROWS*HDIM;           // NROWS
    int*   deg    = (int*)(x_cur + NROWS);              // NNODE
    int*   offs   = deg + NNODE;                        // NNODE+1
    int*   curs   = offs + NNODE + 1;                   // NNODE
    int*   wpart  = curs + NNODE;                       // WPAR+1
    int*   wpart2 = wpart + WPAR + 1;                   // WPAR2+1
    int*   esrc   = wpart2 + WPAR2 + 1;                 // NE
    float* xn_all = (float*)(esrc + NE) + 16;
    xn_all = (float*)(((size_t)xn_all + 255) & ~(size_t)255);
    float* xg_all = xn_all + T_CHUNK*SZ_T;              // 3 * T_CHUNK * SZ_T
    const long K_STRIDE = T_CHUNK*SZ_T;

    hipMemsetAsync(h, 0, (size_t)3*NROWS*HDIM*sizeof(float), stream);
    hipMemsetAsync(deg, 0, NNODE*sizeof(int), stream);

    const int gE = (NE+255)/256;
    csr_count_k<<<gE,256,0,stream>>>(dst, deg);
    csr_scan_k<<<1,1024,0,stream>>>(deg, offs, curs);
    csr_fill_k<<<gE,256,0,stream>>>(dst, src, curs, esrc);
    csr_part_k<<<(WPAR+256)/256,256,0,stream>>>(offs, wpart, WPAR);
    csr_part_k<<<(WPAR2+256)/256,256,0,stream>>>(offs, wpart2, WPAR2);

    const int gRow = (NROWS+255)/256;     // 272

    // ---------------- history phase (batched GNN, sequential GRU) ----------------
    for (int t0 = 0; t0 < HIST-1; t0 += (int)T_CHUNK){
        int T = min((int)T_CHUNK, HIST-1-t0);
        build_hist_k<<<(int)(((long)T*NROWS+255)/256),256,0,stream>>>(x_hist, enc_misc, t0, T, xn_all);
        int gH = 2048 * ((T+7)/8);        // XCD-bound: slice ti -> XCD ti%8
        gnn_gather_t<1><<<gH,256,0,stream>>>(xn_all,            We,be,esrc,offs,wpart, T, xg_all);
        gnn_gather_t<1><<<gH,256,0,stream>>>(xg_all,            We,be,esrc,offs,wpart, T, xg_all+K_STRIDE);
        gnn_gather_t<1><<<gH,256,0,stream>>>(xg_all+K_STRIDE,   We,be,esrc,offs,wpart, T, xg_all+2*K_STRIDE);
        for (int ti=0; ti<T; ti++){
            dim3 gU(NNODE, 3);
            gru3_k<<<gU,256,0,stream>>>(xg_all + ti*SZ_T, K_STRIDE,
                                        xn_all + ti*SZ_T, h, Wx, Wh, bx, bh);
        }
    }

    // ---------------- prediction phase (sequential) ----------------
    for (int p=0;p<PRED;p++){
        if (p==0)
            build_xn_k<<<gRow,256,0,stream>>>(x_hist, 0, dec, p, xn_all);
        else
            build_xn_k<<<gRow,256,0,stream>>>(x_cur, 1, dec, p, xn_all);
        const int gP = WPAR2*64/256;      // 2048 blocks, fine partition
        gnn_gather_t<0><<<gP,256,0,stream>>>(xn_all,          We,be,esrc,offs,wpart2, 1, xg_all);
        gnn_gather_t<0><<<gP,256,0,stream>>>(xg_all,          We,be,esrc,offs,wpart2, 1, xg_all+K_STRIDE);
        gnn_gather_t<0><<<gP,256,0,stream>>>(xg_all+K_STRIDE, We,be,esrc,offs,wpart2, 1, xg_all+2*K_STRIDE);
        dim3 gU(NNODE, 3);
        gru3_k<<<gU,256,0,stream>>>(xg_all, K_STRIDE, xn_all, h, Wx, Wh, bx, bh);
        fc_k<<<gRow,256,0,stream>>>(h, fc_w, fc_b, x_cur, out, p);
    }
}

// Round 8
// 26388.086 us; speedup vs baseline: 1.1068x; 1.1068x over previous
//
#include <hip/hip_runtime.h>
#include <hip/hip_cooperative_groups.h>
namespace cg = cooperative_groups;

#define NB 64
#define NNODE 1085
#define HIST 24
#define PRED 24
#define HDIM 64
#define FMD 11
#define FD 12
#define NE 17360
#define NROWS (NB*NNODE)     // 69440
#define GBLK2 504            // 3 hops x 168 blocks (2 blocks/CU)
#define GBLK1 252            // 3 hops x 84 blocks (1 block/CU fallback)
#define NWAVE_MAX (GBLK2*4)
#define SZT ((long)NROWS*FD) // floats per t-slice

// Layout: node tensors (t, n, f, b): addr = ((t*NNODE+n)*FD + f)*64 + b
// h: (k, row=n*64+b, HDIM)

typedef float v4 __attribute__((ext_vector_type(4)));

__device__ __forceinline__ float sigm(float x){ return 1.0f/(1.0f + __expf(-x)); }
__device__ __forceinline__ float tanh_f(float x){ return 1.0f - 2.0f/(__expf(2.0f*x)+1.0f); }

// ---------------- CSR build ----------------
__global__ void csr_count_k(const int* __restrict__ dst, int* __restrict__ deg)
{
    int e = blockIdx.x*256 + threadIdx.x;
    if (e < NE) atomicAdd(&deg[dst[e]], 1);
}

__global__ __launch_bounds__(1024) void csr_scan_k(const int* __restrict__ deg,
                                                   int* __restrict__ offs, int* __restrict__ curs)
{
    __shared__ int s[2][2048];
    int t = threadIdx.x;
    for (int i=t;i<2048;i+=1024) s[0][i] = (i<NNODE) ? deg[i] : 0;
    __syncthreads();
    int cur = 0;
    for (int d=1; d<2048; d<<=1){
        for (int i=t;i<2048;i+=1024){
            int v = s[cur][i];
            if (i>=d) v += s[cur][i-d];
            s[cur^1][i] = v;
        }
        __syncthreads();
        cur ^= 1;
    }
    for (int i=t;i<=NNODE;i+=1024){
        int v = (i==0) ? 0 : s[cur][i-1];
        offs[i] = v;
        if (i<NNODE) curs[i] = v;
    }
}

__global__ void csr_fill_k(const int* __restrict__ dst, const int* __restrict__ src,
                           int* __restrict__ curs, int* __restrict__ esrc)
{
    int e = blockIdx.x*256 + threadIdx.x;
    if (e < NE){
        int d = dst[e];
        int p = atomicAdd(&curs[d], 1);
        esrc[p] = src[e];
    }
}

__global__ void csr_part_k(const int* __restrict__ offs, int* __restrict__ wpart, int npart)
{
    int w = blockIdx.x*256 + threadIdx.x;
    if (w > npart) return;
    if (w == 0)     { wpart[0] = 0;         return; }
    if (w == npart) { wpart[npart] = NNODE; return; }
    int target = (int)(((long)w * NE) / npart);
    int lo = 0, hi = NNODE;
    while (lo < hi){ int mid = (lo+hi)>>1; if (offs[mid] >= target) hi = mid; else lo = mid+1; }
    wpart[w] = lo;
}

// ---------------- hist feature build (all 23 slices, 1 dispatch) ----------------
__global__ void build_hist_k(const float* __restrict__ x_hist, const float* __restrict__ enc_misc,
                             float* __restrict__ xn_hist)
{
    long idx = (long)blockIdx.x*256 + threadIdx.x;
    if (idx >= (long)(HIST-1)*NROWS) return;
    int b = (int)(idx & 63);
    long nn = idx >> 6;
    int ti = (int)(nn / NNODE);
    int n  = (int)(nn - (long)ti*NNODE);
    float* xp = xn_hist + (long)ti*SZT + (long)n*FD*64 + b;
    xp[0] = x_hist[((long)b*HIST + ti)*NNODE + n];
    const float* fp = enc_misc + (((long)b*HIST + (ti+1))*NNODE + n)*FMD;
    #pragma unroll
    for (int i=0;i<FMD;i++) xp[(1+i)*64] = fp[i];
}

// ---------------- THE cooperative kernel: all 47 steps ----------------
// LDS: W_s 33792 + A_s 11264 + wg 1152 + be 48 = 46256 B  -> 2 blocks/CU safe.
__global__ __launch_bounds__(256,2) void coop_k(
    const float* __restrict__ x_hist, const float* __restrict__ dec,
    float* __restrict__ xn_hist, float* __restrict__ xnp,
    float* __restrict__ xga, float* __restrict__ xgb, float* __restrict__ xgc,
    float* __restrict__ h,
    const float* __restrict__ Wx, const float* __restrict__ Wh,
    const float* __restrict__ bx, const float* __restrict__ bh,
    const float* __restrict__ fc_w, const float* __restrict__ fc_b,
    const float* __restrict__ We, const float* __restrict__ be,
    const int* __restrict__ esrc, const int* __restrict__ offs,
    const int* __restrict__ wpart, float* __restrict__ out)
{
    __shared__ __align__(16) float W_s[44][192];   // one K-chunk, restaged per node-tile
    __shared__ __align__(16) float A_s[44][64];
    __shared__ float wg_s[288];
    __shared__ float beg_s[12];

    cg::grid_group grid = cg::this_grid();
    const int tid = threadIdx.x;
    const int bph  = gridDim.x/3;
    const int hop  = blockIdx.x / bph;
    const int hidx = blockIdx.x - hop*bph;
    const int nn0 = (hidx*NNODE)/bph, nn1 = ((hidx+1)*NNODE)/bph;
    const int tx = tid & 15, ty = tid >> 4;
    const int lane = tid & 63;
    const int wave = blockIdx.x*4 + (tid>>6);

    // one-time staging (edge-MLP weights only)
    for (int i=tid;i<288;i+=256) wg_s[i]=We[i];
    if (tid<12) beg_s[tid]=be[tid];
    __syncthreads();

    const v4* wx4 = (const v4*)(Wx + (size_t)hop*24*192);
    const v4* wh4 = (const v4*)(Wh + (size_t)hop*64*192);
    const float* bxk = bx + hop*192;
    const float* bhk = bh + hop*192;

    // ---- gather phase: edge-parallel, lane=batch, register accumulation ----
    auto gather_phase = [&](const float* __restrict__ x, float* __restrict__ xo){
        const int n0 = wpart[wave], n1 = wpart[wave+1];
        for (int n=n0; n<n1; ++n){
            float xd[12], part[12], acc[12];
            const float* xb = x + (long)n*768 + lane;
            #pragma unroll
            for (int f=0;f<12;f++) xd[f] = xb[f*64];
            #pragma unroll
            for (int f=0;f<12;f++){ part[f]=beg_s[f]; acc[f]=0.f; }
            #pragma unroll
            for (int f=0;f<12;f++){
                float xv = xd[f];
                const float* wrow = &wg_s[(12+f)*12];
                #pragma unroll
                for (int j=0;j<12;j++) part[j] += xv*wrow[j];
            }
            const int e0 = offs[n], e1 = offs[n+1];
            for (int idx=e0; idx<e1; ++idx){
                int s2 = esrc[idx];
                const float* xsb = x + (long)s2*768 + lane;
                float m[12];
                #pragma unroll
                for (int f=0;f<12;f++) m[f]=part[f];
                #pragma unroll
                for (int f=0;f<12;f++){
                    float xv = xsb[f*64];
                    const float* wrow = &wg_s[f*12];
                    #pragma unroll
                    for (int j=0;j<12;j++) m[j] += xv*wrow[j];
                }
                #pragma unroll
                for (int f=0;f<12;f++) acc[f] += fmaxf(m[f],0.f);
            }
            float* xob = xo + (long)n*768 + lane;
            #pragma unroll
            for (int f=0;f<12;f++) xob[f*64] = xd[f] + acc[f];
        }
    };

    // ---- GRU phase: my hop, my nodes (W restaged per node-tile, like gru3_k) ----
    auto gru_phase = [&](const float* __restrict__ xgsl, const float* __restrict__ xnsl){
        v4 bxr=*(const v4*)&bxk[tx*4],     bhr=*(const v4*)&bhk[tx*4];
        v4 bxz=*(const v4*)&bxk[64+tx*4],  bhz=*(const v4*)&bhk[64+tx*4];
        v4 bxn=*(const v4*)&bxk[128+tx*4], bhn=*(const v4*)&bhk[128+tx*4];
        for (int n=nn0; n<nn1; ++n){
            const v4* xg4 = (const v4*)(xgsl + (long)n*768);
            const v4* xn4 = (const v4*)(xnsl + (long)n*768);
            float* hn = h + ((size_t)hop*NROWS + (long)n*64)*HDIM;
            const v4* h4 = (const v4*)hn;
            float ar[16], az[16], agn[16], agh[16];
            #pragma unroll
            for (int i=0;i<16;i++){ ar[i]=0.f; az[i]=0.f; agn[i]=0.f; agh[i]=0.f; }

            __syncthreads();   // guard W_s/A_s from previous reads
            // stage chunk0: W rows 0..43 = [Wx | Wh rows 0..19]; A = [xg|xn|h cols 0..19]
            for (int i=tid; i<44*48; i+=256){
                int kk = i/48, q = i - kk*48;
                *(v4*)&W_s[kk][q*4] = (kk<24) ? wx4[kk*48+q] : wh4[(kk-24)*48+q];
            }
            for (int i=tid; i<192; i+=256) ((v4*)A_s)[i]     = xg4[i];
            for (int i=tid; i<192; i+=256) ((v4*)A_s)[192+i] = xn4[i];
            for (int i=tid; i<320; i+=256){
                int r = i/5, q = i - r*5;
                v4 v = h4[r*16+q];
                #pragma unroll
                for (int j=0;j<4;j++) A_s[24+4*q+j][r] = v[j];
            }
            __syncthreads();
            #pragma unroll 4
            for (int kk=0;kk<24;kk++){
                v4 av=*(const v4*)&A_s[kk][ty*4];
                v4 wr=*(const v4*)&W_s[kk][tx*4];
                v4 wz=*(const v4*)&W_s[kk][64+tx*4];
                v4 wn=*(const v4*)&W_s[kk][128+tx*4];
                #pragma unroll
                for (int dr=0;dr<4;dr++)
                    #pragma unroll
                    for (int dc=0;dc<4;dc++){
                        ar[dr*4+dc]+=av[dr]*wr[dc];
                        az[dr*4+dc]+=av[dr]*wz[dc];
                        agn[dr*4+dc]+=av[dr]*wn[dc];
                    }
            }
            #pragma unroll 4
            for (int kk=24;kk<44;kk++){
                v4 av=*(const v4*)&A_s[kk][ty*4];
                v4 wr=*(const v4*)&W_s[kk][tx*4];
                v4 wz=*(const v4*)&W_s[kk][64+tx*4];
                v4 wn=*(const v4*)&W_s[kk][128+tx*4];
                #pragma unroll
                for (int dr=0;dr<4;dr++)
                    #pragma unroll
                    for (int dc=0;dc<4;dc++){
                        ar[dr*4+dc]+=av[dr]*wr[dc];
                        az[dr*4+dc]+=av[dr]*wz[dc];
                        agh[dr*4+dc]+=av[dr]*wn[dc];
                    }
            }
            __syncthreads();
            // stage chunk1: W rows = Wh rows 20..63; A = h cols 20..63
            for (int i=tid; i<44*48; i+=256){
                int kk = i/48, q = i - kk*48;
                *(v4*)&W_s[kk][q*4] = wh4[(20+kk)*48+q];
            }
            for (int i=tid; i<704; i+=256){
                int r = i/11, q = i - r*11;
                v4 v = h4[r*16+5+q];
                #pragma unroll
                for (int j=0;j<4;j++) A_s[4*q+j][r] = v[j];
            }
            __syncthreads();
            #pragma unroll 4
            for (int kk=0;kk<44;kk++){
                v4 av=*(const v4*)&A_s[kk][ty*4];
                v4 wr=*(const v4*)&W_s[kk][tx*4];
                v4 wz=*(const v4*)&W_s[kk][64+tx*4];
                v4 wn=*(const v4*)&W_s[kk][128+tx*4];
                #pragma unroll
                for (int dr=0;dr<4;dr++)
                    #pragma unroll
                    for (int dc=0;dc<4;dc++){
                        ar[dr*4+dc]+=av[dr]*wr[dc];
                        az[dr*4+dc]+=av[dr]*wz[dc];
                        agh[dr*4+dc]+=av[dr]*wn[dc];
                    }
            }
            #pragma unroll
            for (int dr=0;dr<4;dr++){
                int lr = ty*4 + dr;
                v4 hold = *(const v4*)&hn[lr*HDIM + tx*4];
                v4 hnew;
                #pragma unroll
                for (int dc=0;dc<4;dc++){
                    float rr = sigm(ar[dr*4+dc] + bxr[dc] + bhr[dc]);
                    float zz = sigm(az[dr*4+dc] + bxz[dc] + bhz[dc]);
                    float nn2 = tanh_f(agn[dr*4+dc] + bxn[dc] + rr*(agh[dr*4+dc] + bhn[dc]));
                    hnew[dc] = (1.0f-zz)*nn2 + zz*hold[dc];
                }
                *(v4*)&hn[lr*HDIM + tx*4] = hnew;
            }
        }
    };

    // ================= history phase =================
    for (int t=0; t<HIST-1; ++t){
        const float* xns = xn_hist + (long)t*SZT;
        gather_phase(xns, xga);  grid.sync();
        gather_phase(xga, xgb);  grid.sync();
        gather_phase(xgb, xgc);  grid.sync();
        gru_phase(hop==0 ? xga : (hop==1 ? xgb : xgc), xns);
        grid.sync();
    }

    // ================= prediction phase =================
    for (long idx = (long)blockIdx.x*256 + tid; idx < NROWS; idx += (long)gridDim.x*256){
        int b = (int)(idx & 63), n = (int)(idx >> 6);
        float* xp = xnp + (long)n*768 + b;
        xp[0] = x_hist[((long)b*HIST + (HIST-1))*NNODE + n];
        const float* fp = dec + (((long)b*PRED + 0)*NNODE + n)*FMD;
        #pragma unroll
        for (int i=0;i<FMD;i++) xp[(1+i)*64] = fp[i];
    }
    grid.sync();

    for (int p=0; p<PRED; ++p){
        gather_phase(xnp, xga);  grid.sync();
        gather_phase(xga, xgb);  grid.sync();
        gather_phase(xgb, xgc);  grid.sync();
        gru_phase(hop==0 ? xga : (hop==1 ? xgb : xgc), xnp);
        grid.sync();
        for (long idx = (long)blockIdx.x*256 + tid; idx < NROWS; idx += (long)gridDim.x*256){
            float acc = fc_b[0];
            #pragma unroll
            for (int k=0;k<3;k++){
                const float* hb = h + ((size_t)k*NROWS + idx)*HDIM;
                const float* wb = fc_w + k*HDIM;
                #pragma unroll
                for (int q=0;q<16;q++){
                    v4 hv=*(const v4*)&hb[q*4];
                    v4 wv=*(const v4*)&wb[q*4];
                    acc += hv[0]*wv[0]+hv[1]*wv[1]+hv[2]*wv[2]+hv[3]*wv[3];
                }
            }
            int b = (int)(idx & 63), n = (int)(idx >> 6);
            out[((long)b*PRED + p)*NNODE + n] = acc;
            if (p < PRED-1){
                float* xp = xnp + (long)n*768 + b;
                xp[0] = acc;
                const float* fp = dec + (((long)b*PRED + (p+1))*NNODE + n)*FMD;
                #pragma unroll
                for (int i=0;i<FMD;i++) xp[(1+i)*64] = fp[i];
            }
        }
        grid.sync();
    }
}

extern "C" void kernel_launch(void* const* d_in, const int* in_sizes, int n_in,
                              void* d_out, int out_size, void* d_ws, size_t ws_size,
                              hipStream_t stream)
{
    const float* x_hist   = (const float*)d_in[0];
    const float* enc_misc = (const float*)d_in[1];
    const float* dec      = (const float*)d_in[2];
    const float* We       = (const float*)d_in[3];
    const float* be       = (const float*)d_in[4];
    const float* Wx       = (const float*)d_in[5];
    const float* Wh       = (const float*)d_in[6];
    const float* bx       = (const float*)d_in[7];
    const float* bh       = (const float*)d_in[8];
    const float* fc_w     = (const float*)d_in[9];
    const float* fc_b     = (const float*)d_in[10];
    const int*   src      = (const int*)d_in[11];
    const int*   dst      = (const int*)d_in[12];
    float* out = (float*)d_out;

    // ---- workspace carve ----
    float* h       = (float*)d_ws;                       // 3*NROWS*HDIM
    float* xn_hist = h + (size_t)3*NROWS*HDIM;           // 23 * SZT
    float* xnp     = xn_hist + (size_t)(HIST-1)*SZT;     // SZT
    float* xga     = xnp + SZT;
    float* xgb     = xga + SZT;
    float* xgc     = xgb + SZT;
    int*   deg     = (int*)(xgc + SZT);                  // NNODE
    int*   offs    = deg + NNODE;                        // NNODE+1
    int*   curs    = offs + NNODE + 1;                   // NNODE
    int*   wpartC  = curs + NNODE;                       // NWAVE_MAX+1
    int*   esrc    = wpartC + NWAVE_MAX + 1;             // NE

    // choose cooperative grid from the occupancy query (the round-7 failure mode)
    int maxB = 0;
    if (hipOccupancyMaxActiveBlocksPerMultiprocessor(&maxB, coop_k, 256, 0) != hipSuccess || maxB < 1)
        maxB = 1;
    const int grid = (maxB >= 2) ? GBLK2 : GBLK1;
    const int nwave = grid*4;

    hipMemsetAsync(h, 0, (size_t)3*NROWS*HDIM*sizeof(float), stream);
    hipMemsetAsync(deg, 0, NNODE*sizeof(int), stream);

    const int gE = (NE+255)/256;
    csr_count_k<<<gE,256,0,stream>>>(dst, deg);
    csr_scan_k<<<1,1024,0,stream>>>(deg, offs, curs);
    csr_fill_k<<<gE,256,0,stream>>>(dst, src, curs, esrc);
    csr_part_k<<<(nwave+256)/256,256,0,stream>>>(offs, wpartC, nwave);

    build_hist_k<<<(int)(((long)(HIST-1)*NROWS+255)/256),256,0,stream>>>(x_hist, enc_misc, xn_hist);

    const float* a_xh = x_hist;  const float* a_dec = dec;
    float* a_xnh = xn_hist; float* a_xnp = xnp;
    float* a_xga = xga; float* a_xgb = xgb; float* a_xgc = xgc;
    float* a_h = h;
    const float* a_Wx = Wx; const float* a_Wh = Wh;
    const float* a_bx = bx; const float* a_bh = bh;
    const float* a_fw = fc_w; const float* a_fb = fc_b;
    const float* a_We = We; const float* a_be = be;
    const int* a_es = esrc; const int* a_of = offs; const int* a_wp = wpartC;
    float* a_out = out;
    void* args[] = {
        (void*)&a_xh, (void*)&a_dec, (void*)&a_xnh, (void*)&a_xnp,
        (void*)&a_xga, (void*)&a_xgb, (void*)&a_xgc, (void*)&a_h,
        (void*)&a_Wx, (void*)&a_Wh, (void*)&a_bx, (void*)&a_bh,
        (void*)&a_fw, (void*)&a_fb, (void*)&a_We, (void*)&a_be,
        (void*)&a_es, (void*)&a_of, (void*)&a_wp, (void*)&a_out
    };
    hipLaunchCooperativeKernel((void*)coop_k, dim3(grid), dim3(256), args, 0, stream);
}

// Round 10
// 24918.921 us; speedup vs baseline: 1.1720x; 1.0590x over previous
//
#include <hip/hip_runtime.h>

#define NB 64
#define NNODE 1085
#define HIST 24
#define PRED 24
#define HDIM 64
#define FMD 11
#define FD 12
#define NE 17360
#define NROWS (NB*NNODE)     // 69440
#define WPARH 1024           // waves per slice, hist gather (256 blocks/slice)
#define WPARP 8192           // waves, pred gather (2048 blocks)
#define SZT ((long)NROWS*FD) // f32 per t-slice, (n,f,b) layout

// Layouts:
//  f32 node tensors (t,n,f,b): addr = ((t*NNODE+n)*FD + f)*64 + b
//  bf16 hi/lo h:  hbf[hop][row][128]  (hi cols 0..63, lo cols 64..127), row = n*64+b
//  bf16 hi/lo Wt: [hop][ncol=192][k=192]  k: 0..23 Wx^T hi, 24..31 zero, 32..95 Wh^T hi,
//                                          96..191 same structure lo

typedef float v4 __attribute__((ext_vector_type(4)));
typedef float f32x4 __attribute__((ext_vector_type(4)));
typedef short short8 __attribute__((ext_vector_type(8)));

__device__ __forceinline__ float sigm(float x){ return 1.0f/(1.0f + __expf(-x)); }
__device__ __forceinline__ float tanh_f(float x){ return 1.0f - 2.0f/(__expf(2.0f*x)+1.0f); }
__device__ __forceinline__ unsigned short f2bf(float f){
    union { float f; unsigned u; } v; v.f = f;
    unsigned r = v.u + 0x7FFF + ((v.u >> 16) & 1);
    return (unsigned short)(r >> 16);
}
__device__ __forceinline__ float bf2f(unsigned short u){
    union { unsigned u; float f; } v; v.u = ((unsigned)u)<<16; return v.f;
}

// ---------------- CSR build ----------------
__global__ void csr_count_k(const int* __restrict__ dst, int* __restrict__ deg)
{
    int e = blockIdx.x*256 + threadIdx.x;
    if (e < NE) atomicAdd(&deg[dst[e]], 1);
}

__global__ __launch_bounds__(1024) void csr_scan_k(const int* __restrict__ deg,
                                                   int* __restrict__ offs, int* __restrict__ curs)
{
    __shared__ int s[2][2048];
    int t = threadIdx.x;
    for (int i=t;i<2048;i+=1024) s[0][i] = (i<NNODE) ? deg[i] : 0;
    __syncthreads();
    int cur = 0;
    for (int d=1; d<2048; d<<=1){
        for (int i=t;i<2048;i+=1024){
            int v = s[cur][i];
            if (i>=d) v += s[cur][i-d];
            s[cur^1][i] = v;
        }
        __syncthreads();
        cur ^= 1;
    }
    for (int i=t;i<=NNODE;i+=1024){
        int v = (i==0) ? 0 : s[cur][i-1];
        offs[i] = v;
        if (i<NNODE) curs[i] = v;
    }
}

__global__ void csr_fill_k(const int* __restrict__ dst, const int* __restrict__ src,
                           int* __restrict__ curs, int* __restrict__ esrc)
{
    int e = blockIdx.x*256 + threadIdx.x;
    if (e < NE){
        int d = dst[e];
        int p = atomicAdd(&curs[d], 1);
        esrc[p] = src[e];
    }
}

__global__ void csr_part_k(const int* __restrict__ offs, int* __restrict__ wpart, int npart)
{
    int w = blockIdx.x*256 + threadIdx.x;
    if (w > npart) return;
    if (w == 0)     { wpart[0] = 0;         return; }
    if (w == npart) { wpart[npart] = NNODE; return; }
    int target = (int)(((long)w * NE) / npart);
    int lo = 0, hi = NNODE;
    while (lo < hi){ int mid = (lo+hi)>>1; if (offs[mid] >= target) hi = mid; else lo = mid+1; }
    wpart[w] = lo;
}

// ---------------- one-time prep: W -> transposed hi/lo bf16, bias pack ----------------
__global__ void prep_k(const float* __restrict__ Wx, const float* __restrict__ Wh,
                       const float* __restrict__ bx, const float* __restrict__ bh,
                       unsigned short* __restrict__ Wt, float* __restrict__ bpack)
{
    int id = blockIdx.x*256 + threadIdx.x;
    if (id < 3*192*192){
        int hop = id/(192*192); int rem = id - hop*192*192;
        int n = rem/192, kk = rem - n*192;
        int k2 = (kk < 96) ? kk : kk - 96;
        float v = 0.f;
        if (k2 < 24)       v = Wx[hop*24*192 + k2*192 + n];
        else if (k2 >= 32) v = Wh[hop*64*192 + (k2-32)*192 + n];
        unsigned short hi = f2bf(v);
        Wt[id] = (kk < 96) ? hi : f2bf(v - bf2f(hi));
    }
    if (id < 3*4*64){
        int hop = id/256; int rem = id - hop*256;
        int g = rem>>6, c = rem&63;
        const float* bxk = bx + hop*192; const float* bhk = bh + hop*192;
        float v;
        if (g==0)      v = bxk[c]     + bhk[c];
        else if (g==1) v = bxk[64+c]  + bhk[64+c];
        else if (g==2) v = bxk[128+c];
        else           v = bhk[128+c];
        bpack[id] = v;
    }
}

// ---------------- hist feature build ----------------
__global__ void build_hist_k(const float* __restrict__ x_hist, const float* __restrict__ enc_misc,
                             int t0, int T, float* __restrict__ xn_all)
{
    long idx = (long)blockIdx.x*256 + threadIdx.x;
    if (idx >= (long)T*NROWS) return;
    int b = (int)(idx & 63);
    long nn = idx >> 6;
    int ti = (int)(nn / NNODE);
    int n  = (int)(nn - (long)ti*NNODE);
    int t  = t0 + ti;
    float* xp = xn_all + (long)ti*SZT + (long)n*FD*64 + b;
    xp[0] = x_hist[((long)b*HIST + t)*NNODE + n];
    const float* fp = enc_misc + (((long)b*HIST + (t+1))*NNODE + n)*FMD;
    #pragma unroll
    for (int i=0;i<FMD;i++) xp[(1+i)*64] = fp[i];
}

// ---------------- pred feature build ----------------
__global__ void build_xn_k(const float* __restrict__ xsrc, int from_xcur,
                           const float* __restrict__ dec, int p,
                           float* __restrict__ xn)
{
    int idx = blockIdx.x*256 + threadIdx.x;
    if (idx >= NROWS) return;
    int b = idx & 63, n = idx >> 6;
    float v0 = from_xcur ? xsrc[idx] : xsrc[((long)b*HIST + (HIST-1))*NNODE + n];
    float* xp = xn + (long)n*FD*64 + b;
    xp[0] = v0;
    const float* fp = dec + (((long)b*PRED + p)*NNODE + n)*FMD;
    #pragma unroll
    for (int i=0;i<FMD;i++) xp[(1+i)*64] = fp[i];
}

// ---------------- GNN hop: lane=batch, wave=node-range ----------------
__global__ __launch_bounds__(256,4) void gnn_gather_k(const float* __restrict__ xin,
    const float* __restrict__ We, const float* __restrict__ be,
    const int* __restrict__ esrc, const int* __restrict__ offs,
    const int* __restrict__ wpart, float* __restrict__ xout)
{
    __shared__ float w_s[288];
    __shared__ float be_s[12];
    const int tid = threadIdx.x;
    for (int i=tid;i<288;i+=256) w_s[i]=We[i];
    if (tid<12) be_s[tid]=be[tid];
    __syncthreads();

    const int lane = tid & 63;
    const int wave = (blockIdx.x*256 + tid) >> 6;
    const long ti = blockIdx.y;
    const float* x = xin + ti*SZT;
    float* xo = xout + ti*SZT;

    const int n0 = wpart[wave], n1 = wpart[wave+1];
    for (int n=n0; n<n1; ++n){
        float xd[12], part[12], acc[12];
        const float* xb = x + (long)n*768 + lane;
        #pragma unroll
        for (int f=0;f<12;f++) xd[f] = xb[f*64];
        #pragma unroll
        for (int f=0;f<12;f++){ part[f]=be_s[f]; acc[f]=0.f; }
        #pragma unroll
        for (int f=0;f<12;f++){
            float xv = xd[f];
            const float* wrow = &w_s[(12+f)*12];
            #pragma unroll
            for (int j=0;j<12;j++) part[j] += xv*wrow[j];
        }
        const int e0 = offs[n], e1 = offs[n+1];
        for (int idx=e0; idx<e1; ++idx){
            int s2 = esrc[idx];
            const float* xsb = x + (long)s2*768 + lane;
            float m[12];
            #pragma unroll
            for (int f=0;f<12;f++) m[f]=part[f];
            #pragma unroll
            for (int f=0;f<12;f++){
                float xv = xsb[f*64];
                const float* wrow = &w_s[f*12];
                #pragma unroll
                for (int j=0;j<12;j++) m[j] += xv*wrow[j];
            }
            #pragma unroll
            for (int f=0;f<12;f++) acc[f] += fmaxf(m[f],0.f);
        }
        float* xob = xo + (long)n*768 + lane;
        #pragma unroll
        for (int f=0;f<12;f++) xob[f*64] = xd[f] + acc[f];
    }
}

// ---------------- split-precision MFMA GRU: grid (NNODE, 3 hops) ----------------
__global__ __launch_bounds__(256,2) void gru_mfma_k(
    const float* __restrict__ xg_base, long k_stride,   // hop-k xg = xg_base + k*k_stride
    const float* __restrict__ xn,
    const unsigned short* __restrict__ Wt,              // [hop][192][192]
    const float* __restrict__ bpack,                    // [hop][4][64]
    unsigned short* __restrict__ hbf)                   // [hop][NROWS][128] hi/lo
{
    __shared__ __align__(16) unsigned short Wt_s[192][200];
    const int tid = threadIdx.x;
    const int n = blockIdx.x, hop = blockIdx.y;

    const unsigned short* wtg = Wt + (size_t)hop*192*192;
    #pragma unroll
    for (int it=0; it<18; ++it){
        int i = tid + it*256;                 // 4608 short8 chunks
        int r = i/24, o = i - r*24;
        *(short8*)&Wt_s[r][o*8] = *(const short8*)&wtg[r*192 + o*8];
    }
    __syncthreads();

    const int w = tid>>6, l = tid&63, lr = l&15, lk = l>>4;
    const int b = w*16 + lr;
    const long rowA = (long)n*64 + b;

    // x-part A fragment: k = lk*8..+7 of [xg(12) | xn(12) | pad(8)]; split hi/lo
    short8 a0hi = short8(0), a0lo = short8(0);
    if (lk < 3){
        const float* xgn = xg_base + (long)hop*k_stride + (long)n*768 + b;
        const float* xnn = xn + (long)n*768 + b;
        #pragma unroll
        for (int i=0;i<8;i++){
            int k = lk*8 + i;
            float v = (k<12) ? xgn[k*64] : xnn[(k-12)*64];
            unsigned short hi = f2bf(v);
            a0hi[i] = (short)hi;
            a0lo[i] = (short)f2bf(v - bf2f(hi));
        }
    }
    const unsigned short* hb = hbf + ((long)hop*NROWS + rowA)*128;
    short8 a1hi = *(const short8*)&hb[lk*8];
    short8 a2hi = *(const short8*)&hb[32 + lk*8];
    short8 a1lo = *(const short8*)&hb[64 + lk*8];
    short8 a2lo = *(const short8*)&hb[96 + lk*8];

    f32x4 accRZ[8], accNX[4], accNH[4];
    #pragma unroll
    for (int i=0;i<8;i++) accRZ[i] = f32x4(0.f);
    #pragma unroll
    for (int i=0;i<4;i++){ accNX[i] = f32x4(0.f); accNH[i] = f32x4(0.f); }

    #pragma unroll
    for (int nt=0; nt<12; ++nt){
        const unsigned short* wc = &Wt_s[nt*16 + lr][0];
        short8 b0h = *(const short8*)&wc[lk*8];
        short8 b1h = *(const short8*)&wc[32 + lk*8];
        short8 b2h = *(const short8*)&wc[64 + lk*8];
        short8 b0l = *(const short8*)&wc[96 + lk*8];
        short8 b1l = *(const short8*)&wc[128 + lk*8];
        short8 b2l = *(const short8*)&wc[160 + lk*8];
        if (nt < 8){
            f32x4 acc = accRZ[nt];
            acc = __builtin_amdgcn_mfma_f32_16x16x32_bf16(a0hi, b0h, acc, 0,0,0);
            acc = __builtin_amdgcn_mfma_f32_16x16x32_bf16(a0lo, b0h, acc, 0,0,0);
            acc = __builtin_amdgcn_mfma_f32_16x16x32_bf16(a0hi, b0l, acc, 0,0,0);
            acc = __builtin_amdgcn_mfma_f32_16x16x32_bf16(a1hi, b1h, acc, 0,0,0);
            acc = __builtin_amdgcn_mfma_f32_16x16x32_bf16(a1lo, b1h, acc, 0,0,0);
            acc = __builtin_amdgcn_mfma_f32_16x16x32_bf16(a1hi, b1l, acc, 0,0,0);
            acc = __builtin_amdgcn_mfma_f32_16x16x32_bf16(a2hi, b2h, acc, 0,0,0);
            acc = __builtin_amdgcn_mfma_f32_16x16x32_bf16(a2lo, b2h, acc, 0,0,0);
            acc = __builtin_amdgcn_mfma_f32_16x16x32_bf16(a2hi, b2l, acc, 0,0,0);
            accRZ[nt] = acc;
        } else {
            f32x4 ax = accNX[nt-8], ah = accNH[nt-8];
            ax = __builtin_amdgcn_mfma_f32_16x16x32_bf16(a0hi, b0h, ax, 0,0,0);
            ax = __builtin_amdgcn_mfma_f32_16x16x32_bf16(a0lo, b0h, ax, 0,0,0);
            ax = __builtin_amdgcn_mfma_f32_16x16x32_bf16(a0hi, b0l, ax, 0,0,0);
            ah = __builtin_amdgcn_mfma_f32_16x16x32_bf16(a1hi, b1h, ah, 0,0,0);
            ah = __builtin_amdgcn_mfma_f32_16x16x32_bf16(a1lo, b1h, ah, 0,0,0);
            ah = __builtin_amdgcn_mfma_f32_16x16x32_bf16(a1hi, b1l, ah, 0,0,0);
            ah = __builtin_amdgcn_mfma_f32_16x16x32_bf16(a2hi, b2h, ah, 0,0,0);
            ah = __builtin_amdgcn_mfma_f32_16x16x32_bf16(a2lo, b2h, ah, 0,0,0);
            ah = __builtin_amdgcn_mfma_f32_16x16x32_bf16(a2hi, b2l, ah, 0,0,0);
            accNX[nt-8] = ax; accNH[nt-8] = ah;
        }
    }

    const float* bp = bpack + hop*256;
    unsigned short* hbo = hbf + ((long)hop*NROWS + (long)n*64)*128;
    #pragma unroll
    for (int nt0=0; nt0<4; ++nt0){
        int hcol = nt0*16 + lr;
        float br  = bp[hcol];
        float bz  = bp[64 + hcol];
        float bxn = bp[128 + hcol];
        float bhn = bp[192 + hcol];
        #pragma unroll
        for (int i=0;i<4;i++){
            int orow = w*16 + lk*4 + i;        // C/D: row=(lane>>4)*4+reg, col=lane&15
            long off = (long)orow*128 + hcol;
            float hold = bf2f(hbo[off]) + bf2f(hbo[off+64]);
            float r  = sigm(accRZ[nt0][i] + br);
            float z  = sigm(accRZ[4+nt0][i] + bz);
            float nn2 = tanh_f(accNX[nt0][i] + bxn + r*(accNH[nt0][i] + bhn));
            float hv = (1.f - z)*nn2 + z*hold;
            unsigned short hvh = f2bf(hv);
            hbo[off] = hvh;
            hbo[off+64] = f2bf(hv - bf2f(hvh));
        }
    }
}

// ---------------- fc (reads hi/lo h) ----------------
__global__ void fc_k(const unsigned short* __restrict__ hbf, const float* __restrict__ fc_w,
                     const float* __restrict__ fc_b, float* __restrict__ x_cur,
                     float* __restrict__ out, int p)
{
    int idx = blockIdx.x*256+threadIdx.x;
    if (idx>=NROWS) return;
    float acc = fc_b[0];
    #pragma unroll
    for (int k=0;k<3;k++){
        const unsigned short* hb = hbf + ((size_t)k*NROWS + idx)*128;
        const float* wb = fc_w + k*HDIM;
        #pragma unroll
        for (int q=0;q<8;q++){
            short8 hi8 = *(const short8*)&hb[q*8];
            short8 lo8 = *(const short8*)&hb[64 + q*8];
            #pragma unroll
            for (int j=0;j<8;j++)
                acc += (bf2f((unsigned short)hi8[j]) + bf2f((unsigned short)lo8[j])) * wb[q*8+j];
        }
    }
    x_cur[idx]=acc;
    int b = idx & 63, n = idx >> 6;
    out[((long)b*PRED + p)*NNODE + n] = acc;
}

extern "C" void kernel_launch(void* const* d_in, const int* in_sizes, int n_in,
                              void* d_out, int out_size, void* d_ws, size_t ws_size,
                              hipStream_t stream)
{
    const float* x_hist   = (const float*)d_in[0];
    const float* enc_misc = (const float*)d_in[1];
    const float* dec      = (const float*)d_in[2];
    const float* We       = (const float*)d_in[3];
    const float* be       = (const float*)d_in[4];
    const float* Wx       = (const float*)d_in[5];
    const float* Wh       = (const float*)d_in[6];
    const float* bx       = (const float*)d_in[7];
    const float* bh       = (const float*)d_in[8];
    const float* fc_w     = (const float*)d_in[9];
    const float* fc_b     = (const float*)d_in[10];
    const int*   src      = (const int*)d_in[11];
    const int*   dst      = (const int*)d_in[12];
    float* out = (float*)d_out;

    // ---- workspace carve (byte-based, 256-aligned) ----
    char* p = (char*)d_ws;
    auto alloc = [&](size_t bytes) -> char* {
        p = (char*)(((size_t)p + 255) & ~(size_t)255);
        char* r = p; p += bytes; return r;
    };
    unsigned short* hbf = (unsigned short*)alloc((size_t)3*NROWS*128*2);  // 53.3 MB
    unsigned short* Wt  = (unsigned short*)alloc((size_t)3*192*192*2);
    float* bpack = (float*)alloc(3*4*64*4);
    float* x_cur = (float*)alloc((size_t)NROWS*4);
    int* deg    = (int*)alloc(NNODE*4);
    int* offs   = (int*)alloc((NNODE+1)*4);
    int* curs   = (int*)alloc(NNODE*4);
    int* wpartH = (int*)alloc((WPARH+1)*4);
    int* wpartP = (int*)alloc((WPARP+1)*4);
    int* esrc   = (int*)alloc(NE*4);

    const size_t perslice = (size_t)SZT*4*4;     // xn + 3 xg hops, f32
    size_t fixed_used = (size_t)(p - (char*)d_ws) + 8192;
    long T_CHUNK = 1;
    if (ws_size > fixed_used + perslice)
        T_CHUNK = (long)((ws_size - fixed_used) / perslice);
    if (T_CHUNK > HIST-1) T_CHUNK = HIST-1;
    if (T_CHUNK < 1) T_CHUNK = 1;

    float* xn_all = (float*)alloc((size_t)T_CHUNK*SZT*4);
    float* xg_all = (float*)alloc((size_t)3*T_CHUNK*SZT*4);
    const long K_STRIDE = T_CHUNK*SZT;

    hipMemsetAsync(hbf, 0, (size_t)3*NROWS*128*2, stream);
    hipMemsetAsync(deg, 0, NNODE*4, stream);

    const int gE = (NE+255)/256;
    csr_count_k<<<gE,256,0,stream>>>(dst, deg);
    csr_scan_k<<<1,1024,0,stream>>>(deg, offs, curs);
    csr_fill_k<<<gE,256,0,stream>>>(dst, src, curs, esrc);
    csr_part_k<<<(WPARH+256)/256,256,0,stream>>>(offs, wpartH, WPARH);
    csr_part_k<<<(WPARP+256)/256,256,0,stream>>>(offs, wpartP, WPARP);
    prep_k<<<(3*192*192+255)/256,256,0,stream>>>(Wx, Wh, bx, bh, Wt, bpack);

    const int gRow = (NROWS+255)/256;

    // ---------------- history phase ----------------
    for (int t0 = 0; t0 < HIST-1; t0 += (int)T_CHUNK){
        int T = min((int)T_CHUNK, HIST-1-t0);
        build_hist_k<<<(int)(((long)T*NROWS+255)/256),256,0,stream>>>(x_hist, enc_misc, t0, T, xn_all);
        dim3 gH(WPARH/4, T);
        gnn_gather_k<<<gH,256,0,stream>>>(xn_all,             We,be,esrc,offs,wpartH, xg_all);
        gnn_gather_k<<<gH,256,0,stream>>>(xg_all,             We,be,esrc,offs,wpartH, xg_all+K_STRIDE);
        gnn_gather_k<<<gH,256,0,stream>>>(xg_all+K_STRIDE,    We,be,esrc,offs,wpartH, xg_all+2*K_STRIDE);
        for (int ti=0; ti<T; ti++){
            dim3 gU(NNODE, 3);
            gru_mfma_k<<<gU,256,0,stream>>>(xg_all + ti*SZT, K_STRIDE,
                                            xn_all + ti*SZT, Wt, bpack, hbf);
        }
    }

    // ---------------- prediction phase ----------------
    for (int pstep=0; pstep<PRED; pstep++){
        if (pstep==0)
            build_xn_k<<<gRow,256,0,stream>>>(x_hist, 0, dec, pstep, xn_all);
        else
            build_xn_k<<<gRow,256,0,stream>>>(x_cur, 1, dec, pstep, xn_all);
        dim3 gP(WPARP/4, 1);
        gnn_gather_k<<<gP,256,0,stream>>>(xn_all,          We,be,esrc,offs,wpartP, xg_all);
        gnn_gather_k<<<gP,256,0,stream>>>(xg_all,          We,be,esrc,offs,wpartP, xg_all+K_STRIDE);
        gnn_gather_k<<<gP,256,0,stream>>>(xg_all+K_STRIDE, We,be,esrc,offs,wpartP, xg_all+2*K_STRIDE);
        dim3 gU(NNODE, 3);
        gru_mfma_k<<<gU,256,0,stream>>>(xg_all, K_STRIDE, xn_all, Wt, bpack, hbf);
        fc_k<<<gRow,256,0,stream>>>(hbf, fc_w, fc_b, x_cur, out, pstep);
    }
}